// Round 2
// baseline (25874.152 us; speedup 1.0000x reference)
//
#include <hip/hip_runtime.h>
#include <math.h>

#define S_LEN 512
#define BATCH 64
#define IN_DIM 512
#define HID 512
#define DEPTH 5
#define N3 1536  // 3*HID

typedef float floatx4 __attribute__((ext_vector_type(4)));
typedef unsigned int uintx4 __attribute__((ext_vector_type(4)));

// =====================================================================
// Input projection GEMM (unchanged):
//   HTC[m, n] = sum_k (h_mask[m&63, k] * inp[m, k]) * W3[n, k] + b3[n]
// =====================================================================
__global__ __launch_bounds__(256) void rhn_inproj(
    const float* __restrict__ inp, const float* __restrict__ h_mask,
    const float* __restrict__ Wih, const float* __restrict__ Wit,
    const float* __restrict__ Wic, const float* __restrict__ bih,
    const float* __restrict__ bit_, const float* __restrict__ bic,
    float* __restrict__ HTC)
{
    constexpr int BM = 128, BN = 128, BK = 16, LW = BM + 4;
    __shared__ float As[BK][LW];
    __shared__ float Bs[BK][LW];
    const int m0 = blockIdx.x * BM;
    const int n0 = blockIdx.y * BN;
    const int tid = threadIdx.x;
    const int lrow = tid & 127;
    const int lkq  = tid >> 7;
    const int tx = tid & 15, ty = tid >> 4;

    const float* Arow = inp + (size_t)(m0 + lrow) * 512;
    const float* Mrow = h_mask + (size_t)((m0 + lrow) & 63) * 512;
    const int n = n0 + lrow;
    const float* Wrow = (n < 512) ? (Wih + (size_t)n * 512)
                       : (n < 1024) ? (Wit + (size_t)(n - 512) * 512)
                                    : (Wic + (size_t)(n - 1024) * 512);

    float acc[8][8] = {};

    for (int k0 = 0; k0 < 512; k0 += BK) {
#pragma unroll
        for (int it = 0; it < 2; ++it) {
            int kq = lkq * 2 + it;
            float4 av = *(const float4*)(Arow + k0 + kq * 4);
            float4 mv = *(const float4*)(Mrow + k0 + kq * 4);
            float4 bv = *(const float4*)(Wrow + k0 + kq * 4);
            As[kq * 4 + 0][lrow] = av.x * mv.x;
            As[kq * 4 + 1][lrow] = av.y * mv.y;
            As[kq * 4 + 2][lrow] = av.z * mv.z;
            As[kq * 4 + 3][lrow] = av.w * mv.w;
            Bs[kq * 4 + 0][lrow] = bv.x;
            Bs[kq * 4 + 1][lrow] = bv.y;
            Bs[kq * 4 + 2][lrow] = bv.z;
            Bs[kq * 4 + 3][lrow] = bv.w;
        }
        __syncthreads();
#pragma unroll
        for (int kk = 0; kk < BK; ++kk) {
            float4 a0 = *(const float4*)&As[kk][ty * 8];
            float4 a1 = *(const float4*)&As[kk][ty * 8 + 4];
            float4 bv0 = *(const float4*)&Bs[kk][tx * 8];
            float4 bv1 = *(const float4*)&Bs[kk][tx * 8 + 4];
            float am[8] = {a0.x, a0.y, a0.z, a0.w, a1.x, a1.y, a1.z, a1.w};
            float bn[8] = {bv0.x, bv0.y, bv0.z, bv0.w, bv1.x, bv1.y, bv1.z, bv1.w};
#pragma unroll
            for (int i = 0; i < 8; ++i)
#pragma unroll
                for (int j = 0; j < 8; ++j)
                    acc[i][j] += am[i] * bn[j];
        }
        __syncthreads();
    }

    float bias[8];
#pragma unroll
    for (int j = 0; j < 8; ++j) {
        int nn = n0 + tx * 8 + j;
        bias[j] = (nn < 512) ? bih[nn] : (nn < 1024) ? bit_[nn - 512] : bic[nn - 1024];
    }
#pragma unroll
    for (int i = 0; i < 8; ++i) {
        int mm = m0 + ty * 8 + i;
        float4 o0, o1;
        o0.x = acc[i][0] + bias[0]; o0.y = acc[i][1] + bias[1];
        o0.z = acc[i][2] + bias[2]; o0.w = acc[i][3] + bias[3];
        o1.x = acc[i][4] + bias[4]; o1.y = acc[i][5] + bias[5];
        o1.z = acc[i][6] + bias[6]; o1.w = acc[i][7] + bias[7];
        *(float4*)(HTC + (size_t)mm * N3 + n0 + tx * 8)     = o0;
        *(float4*)(HTC + (size_t)mm * N3 + n0 + tx * 8 + 4) = o1;
    }
}

__device__ __forceinline__ float fast_sig(float x) {
    return __builtin_amdgcn_rcpf(1.f + __expf(-x));
}
__device__ __forceinline__ float fast_tanh(float x) {
    return 2.f * fast_sig(2.f * x) - 1.f;
}

// =====================================================================
// Recurrence: 256 blocks x 512 threads, one block/CU.
// Block = (h-tile 16) x (b-group of 8). Thread = (gate g, h-row hl in 16,
// k-chunk kq in 16). W slice (5 layers x 32 floats) lives in REGISTERS.
//
// Exchange protocol (flag/data split):
//   producers store plain masked state (sc1), drain per-wave vmcnt(0),
//   then lane 0 of each owner wave stores a monotonic sub-flag
//   flags[(bi*32+hi)*4 + wave]. Consumers spin on ONE dword flag
//   (128 B/block poll footprint, broadcast), then load their 32 B of
//   state exactly once. 2-slot data ring, monotonic flags (no wrap).
// =====================================================================
__global__ __launch_bounds__(512, 2) void rhn_scan(
    const float* __restrict__ hidden,
    const float* __restrict__ s_h_mask,
    const float* __restrict__ Wh, const float* __restrict__ bh,
    const float* __restrict__ Wt, const float* __restrict__ bt,
    const float* __restrict__ HTC,
    float* __restrict__ exch,        // [2][64][512] masked-state ring
    unsigned* __restrict__ flags,    // [8][32][4] monotonic sub-flags
    float* __restrict__ out)         // outs [512][64][512] then last [64][512]
{
    __shared__ float sm_s[8][HID];   // masked state, [b-local][k]
    __shared__ float linT[16][8];    // lin_t exchange g1 -> g0

    const int tid  = threadIdx.x;
    const int lane = tid & 63;
    const int w    = tid >> 6;          // wave 0..7
    const int c    = lane & 3;
    const int kq   = (lane >> 2) & 15;  // k-chunk, in lane bits [5:2] for shfl
    const int gh   = w * 4 + c;         // 0..31
    const int g    = gh >> 4;           // 0: Wh side, 1: Wt side
    const int hl   = gh & 15;           // h-row within tile

    const int hi = blockIdx.x >> 3;     // 0..31 h-split
    const int bi = blockIdx.x & 7;      // 0..7  b-group
    const int h0 = hi * 16, b0 = bi * 8;

    // b owned after kq-reduction (dup at kq and kq+8)
    const int myb = ((kq & 1) << 2) | (kq & 2) | ((kq >> 2) & 1);
    const bool own = (g == 0) && (kq < 8);   // owners live in waves 0..3
    const bool lw  = (g == 1) && (kq < 8);

    // ---- one-time: W slice into registers (5 layers x 8 float4) ----
    const float* Wsrc = g ? Wt : Wh;
    float4 Wreg[DEPTH * 8];
#pragma unroll
    for (int l = 0; l < DEPTH; ++l)
#pragma unroll
        for (int j = 0; j < 8; ++j)
            Wreg[l * 8 + j] = *(const float4*)(Wsrc
                + ((size_t)l * HID + (h0 + hl)) * HID + (size_t)(j * 16 + kq) * 4);

    float biasr[DEPTH];
    const float* bsrc = g ? bt : bh;
#pragma unroll
    for (int l = 0; l < DEPTH; ++l) biasr[l] = bsrc[l * HID + h0 + hl];

    // ---- staging slots: each thread owns 2 float4 of the [8][512] state ----
    // pB = tid+512 has the SAME k-index as pA -> one producer sub-flag/thread
    const int bA = tid >> 7,  kA = tid & 127;   // b 0..3
    const int bB = bA + 4,    kB = kA;          // b 4..7
    const size_t offA = ((size_t)(b0 + bA) * HID + (size_t)kA * 4) * sizeof(float);
    const size_t offB = ((size_t)(b0 + bB) * HID + (size_t)kB * 4) * sizeof(float);
    const size_t SLOT = (size_t)BATCH * HID * sizeof(float);

    // consumer flag: producer block hiA = kA>>2, owner wave sub = kA&3
    const unsigned* fp = flags + (((size_t)bi * 32 + (kA >> 2)) * 4 + (kA & 3));
    // producer flag (owner waves 0..3 only)
    unsigned* fme = flags + (((size_t)bi * 32 + hi) * 4 + w);

    // ---- owner-held state (128 owners/block: g==0 && kq<8) ----
    float s = 0.f, mymask = 0.f, Hp = 0.f, Tp = 0.f, Cp = 0.f;
    size_t ownoff = 0;
    if (own) {
        const int gb = b0 + myb, hh = h0 + hl;
        s      = hidden[(size_t)gb * HID + hh];
        mymask = s_h_mask[(size_t)gb * HID + hh];
        const float* hp = HTC + (size_t)gb * N3 + hh;   // step 0
        Hp = hp[0]; Tp = hp[512]; Cp = hp[1024];
        ownoff = ((size_t)gb * HID + hh) * sizeof(float);
        // publish exchange #0 (slot 0): masked initial state
        float v = s * mymask;
        char* p = (char*)exch + ownoff;
        asm volatile("global_store_dword %0, %1, off sc1" :: "v"(p), "v"(v) : "memory");
    }
    if (w < 4) {
        asm volatile("s_waitcnt vmcnt(0)" ::: "memory");
        if (lane == 0) {
            unsigned one = 1u;
            asm volatile("global_store_dword %0, %1, off sc1"
                         :: "v"(fme), "v"(one) : "memory");
        }
    }

    const float4* smq = (const float4*)&sm_s[0][0] + kq;

    int seq = 0;
    for (int step = 0; step < S_LEN; ++step) {
#define ROUND(L)                                                                  \
        {                                                                         \
            const unsigned target = (unsigned)(seq + 1);                          \
            const char* sb = (const char*)exch + (size_t)(seq & 1) * SLOT;        \
            const char* pa = sb + offA;                                           \
            const char* pb = sb + offB;                                           \
            unsigned fv;                                                          \
            for (;;) {                                                            \
                asm volatile("global_load_dword %0, %1, off sc1\n\t"              \
                             "s_waitcnt vmcnt(0)"                                 \
                             : "=v"(fv) : "v"(fp) : "memory");                    \
                if (fv >= target) break;                                          \
            }                                                                     \
            uintx4 ua, ub;                                                        \
            asm volatile("global_load_dwordx4 %0, %2, off sc1\n\t"                \
                         "global_load_dwordx4 %1, %3, off sc1\n\t"                \
                         "s_waitcnt vmcnt(0)"                                     \
                         : "=&v"(ua), "=&v"(ub)                                   \
                         : "v"(pa), "v"(pb) : "memory");                          \
            *(uintx4*)&sm_s[bA][kA * 4] = ua;                                     \
            *(uintx4*)&sm_s[bB][kB * 4] = ub;                                     \
            __syncthreads();  /* sync1: staging complete */                       \
            float acc[8] = {0.f, 0.f, 0.f, 0.f, 0.f, 0.f, 0.f, 0.f};              \
            _Pragma("unroll")                                                     \
            for (int j = 0; j < 8; ++j) {                                         \
                const float4 wv = Wreg[(L) * 8 + j];                              \
                _Pragma("unroll")                                                 \
                for (int b = 0; b < 8; ++b) {                                     \
                    const float4 sv = smq[b * 128 + j * 16];                      \
                    acc[b] = fmaf(wv.x, sv.x, acc[b]);                            \
                    acc[b] = fmaf(wv.y, sv.y, acc[b]);                            \
                    acc[b] = fmaf(wv.z, sv.z, acc[b]);                            \
                    acc[b] = fmaf(wv.w, sv.w, acc[b]);                            \
                }                                                                 \
            }                                                                     \
            {   /* reduce over kq (lane bits 2..5), pair-combining tree */        \
                const bool u0 = (lane & 4) != 0;                                  \
                const bool u1 = (lane & 8) != 0;                                  \
                const bool u2 = (lane & 16) != 0;                                 \
                _Pragma("unroll")                                                 \
                for (int i = 0; i < 4; ++i) {                                     \
                    float snd = u0 ? acc[i] : acc[i + 4];                         \
                    float kp  = u0 ? acc[i + 4] : acc[i];                         \
                    acc[i] = kp + __shfl_xor(snd, 4);                             \
                }                                                                 \
                _Pragma("unroll")                                                 \
                for (int i = 0; i < 2; ++i) {                                     \
                    float snd = u1 ? acc[i] : acc[i + 2];                         \
                    float kp  = u1 ? acc[i + 2] : acc[i];                         \
                    acc[i] = kp + __shfl_xor(snd, 8);                             \
                }                                                                 \
                {                                                                 \
                    float snd = u2 ? acc[0] : acc[1];                             \
                    float kp  = u2 ? acc[1] : acc[0];                             \
                    acc[0] = kp + __shfl_xor(snd, 16);                            \
                }                                                                 \
                acc[0] += __shfl_xor(acc[0], 32);                                 \
            }                                                                     \
            const float lin = acc[0] + biasr[L];                                  \
            if (lw) linT[hl][myb] = lin;                                          \
            __syncthreads();  /* sync2: linT ready; all dots done */              \
            if (own) {                                                            \
                const float lt = linT[hl][myb];                                   \
                float hv, tv, cv;                                                 \
                if ((L) == 0) {                                                   \
                    hv = fast_tanh(Hp + lin);                                     \
                    tv = fast_sig(Tp + lt);                                       \
                    cv = fast_sig(Cp + lt);                                       \
                } else {                                                          \
                    hv = fast_tanh(lin);                                          \
                    tv = fast_sig(lt);                                            \
                    cv = tv;                                                      \
                }                                                                 \
                s = hv * tv + s * cv;                                             \
                float v = s * mymask;                                             \
                char* p = (char*)exch + (size_t)((seq + 1) & 1) * SLOT + ownoff;  \
                asm volatile("global_store_dword %0, %1, off sc1"                 \
                             :: "v"(p), "v"(v) : "memory");                       \
            }                                                                     \
            if (w < 4) {  /* owner waves: drain data, then publish sub-flag */    \
                asm volatile("s_waitcnt vmcnt(0)" ::: "memory");                  \
                if (lane == 0) {                                                  \
                    unsigned nf = (unsigned)(seq + 2);                            \
                    asm volatile("global_store_dword %0, %1, off sc1"             \
                                 :: "v"(fme), "v"(nf) : "memory");                \
                }                                                                 \
            }                                                                     \
            if (own) {  /* non-critical tail: out write + HTC prefetch */         \
                if ((L) == DEPTH - 1)                                             \
                    out[((size_t)step * BATCH + (b0 + myb)) * HID + (h0 + hl)] = s; \
                if ((L) == 0 && step + 1 < S_LEN) {                               \
                    const float* hp = HTC + ((size_t)(step + 1) * BATCH           \
                                      + (b0 + myb)) * N3 + (h0 + hl);             \
                    Hp = hp[0]; Tp = hp[512]; Cp = hp[1024];                      \
                }                                                                 \
            }                                                                     \
            ++seq;                                                                \
        }
        ROUND(0) ROUND(1) ROUND(2) ROUND(3) ROUND(4)
#undef ROUND
    }

    // last = outs[S_LEN-1]
    if (own)
        out[(size_t)S_LEN * BATCH * HID + (size_t)(b0 + myb) * HID + (h0 + hl)] = s;
}

extern "C" void kernel_launch(void* const* d_in, const int* in_sizes, int n_in,
                              void* d_out, int out_size, void* d_ws, size_t ws_size,
                              hipStream_t stream) {
    const float* inp      = (const float*)d_in[0];
    const float* hidden   = (const float*)d_in[1];
    const float* h_mask   = (const float*)d_in[2];
    const float* s_h_mask = (const float*)d_in[3];
    const float* Wih = (const float*)d_in[4];
    const float* bih = (const float*)d_in[5];
    const float* Wit = (const float*)d_in[6];
    const float* bit_ = (const float*)d_in[7];
    const float* Wic = (const float*)d_in[8];
    const float* bic = (const float*)d_in[9];
    const float* Wh = (const float*)d_in[10];
    const float* bh = (const float*)d_in[11];
    const float* Wt = (const float*)d_in[12];
    const float* bt = (const float*)d_in[13];
    float* out = (float*)d_out;

    float* HTC  = (float*)d_ws;                    // 32768*1536 f32 = 201.3 MB
    float* exch = HTC + (size_t)32768 * N3;        // 2*64*512 f32 ring
    unsigned* flags = (unsigned*)(exch + 2 * (size_t)BATCH * HID);  // 8*32*4 dwords

    // zero flags (monotonic counters start at 0 each run)
    (void)hipMemsetAsync(flags, 0, 8 * 32 * 4 * sizeof(unsigned), stream);

    // 1) input projections
    dim3 g1(256, 12);
    rhn_inproj<<<g1, 256, 0, stream>>>(inp, h_mask, Wih, Wit, Wic, bih, bit_, bic, HTC);

    // 2) recurrence (cooperative: guarantees co-residency for the spin protocol)
    void* args[] = {(void*)&hidden, (void*)&s_h_mask, (void*)&Wh, (void*)&bh,
                    (void*)&Wt, (void*)&bt, (void*)&HTC, (void*)&exch,
                    (void*)&flags, (void*)&out};
    (void)hipLaunchCooperativeKernel((void*)rhn_scan, dim3(256), dim3(512), args, 0, stream);
}

// Round 7
// 18999.905 us; speedup vs baseline: 1.3618x; 1.3618x over previous
//
#include <hip/hip_runtime.h>
#include <math.h>

#define S_LEN 512
#define BATCH 64
#define IN_DIM 512
#define HID 512
#define DEPTH 5
#define N3 1536  // 3*HID
#define NBLK 256

typedef float floatx4 __attribute__((ext_vector_type(4)));
typedef unsigned int uintx4 __attribute__((ext_vector_type(4)));

// =====================================================================
// Input projection GEMM (unchanged, proven):
//   HTC[m, n] = sum_k (h_mask[m&63, k] * inp[m, k]) * W3[n, k] + b3[n]
// =====================================================================
__global__ __launch_bounds__(256) void rhn_inproj(
    const float* __restrict__ inp, const float* __restrict__ h_mask,
    const float* __restrict__ Wih, const float* __restrict__ Wit,
    const float* __restrict__ Wic, const float* __restrict__ bih,
    const float* __restrict__ bit_, const float* __restrict__ bic,
    float* __restrict__ HTC)
{
    constexpr int BM = 128, BN = 128, BK = 16, LW = BM + 4;
    __shared__ float As[BK][LW];
    __shared__ float Bs[BK][LW];
    const int m0 = blockIdx.x * BM;
    const int n0 = blockIdx.y * BN;
    const int tid = threadIdx.x;
    const int lrow = tid & 127;
    const int lkq  = tid >> 7;
    const int tx = tid & 15, ty = tid >> 4;

    const float* Arow = inp + (size_t)(m0 + lrow) * 512;
    const float* Mrow = h_mask + (size_t)((m0 + lrow) & 63) * 512;
    const int n = n0 + lrow;
    const float* Wrow = (n < 512) ? (Wih + (size_t)n * 512)
                       : (n < 1024) ? (Wit + (size_t)(n - 512) * 512)
                                    : (Wic + (size_t)(n - 1024) * 512);

    float acc[8][8] = {};

    for (int k0 = 0; k0 < 512; k0 += BK) {
#pragma unroll
        for (int it = 0; it < 2; ++it) {
            int kq = lkq * 2 + it;
            float4 av = *(const float4*)(Arow + k0 + kq * 4);
            float4 mv = *(const float4*)(Mrow + k0 + kq * 4);
            float4 bv = *(const float4*)(Wrow + k0 + kq * 4);
            As[kq * 4 + 0][lrow] = av.x * mv.x;
            As[kq * 4 + 1][lrow] = av.y * mv.y;
            As[kq * 4 + 2][lrow] = av.z * mv.z;
            As[kq * 4 + 3][lrow] = av.w * mv.w;
            Bs[kq * 4 + 0][lrow] = bv.x;
            Bs[kq * 4 + 1][lrow] = bv.y;
            Bs[kq * 4 + 2][lrow] = bv.z;
            Bs[kq * 4 + 3][lrow] = bv.w;
        }
        __syncthreads();
#pragma unroll
        for (int kk = 0; kk < BK; ++kk) {
            float4 a0 = *(const float4*)&As[kk][ty * 8];
            float4 a1 = *(const float4*)&As[kk][ty * 8 + 4];
            float4 bv0 = *(const float4*)&Bs[kk][tx * 8];
            float4 bv1 = *(const float4*)&Bs[kk][tx * 8 + 4];
            float am[8] = {a0.x, a0.y, a0.z, a0.w, a1.x, a1.y, a1.z, a1.w};
            float bn[8] = {bv0.x, bv0.y, bv0.z, bv0.w, bv1.x, bv1.y, bv1.z, bv1.w};
#pragma unroll
            for (int i = 0; i < 8; ++i)
#pragma unroll
                for (int j = 0; j < 8; ++j)
                    acc[i][j] += am[i] * bn[j];
        }
        __syncthreads();
    }

    float bias[8];
#pragma unroll
    for (int j = 0; j < 8; ++j) {
        int nn = n0 + tx * 8 + j;
        bias[j] = (nn < 512) ? bih[nn] : (nn < 1024) ? bit_[nn - 512] : bic[nn - 1024];
    }
#pragma unroll
    for (int i = 0; i < 8; ++i) {
        int mm = m0 + ty * 8 + i;
        float4 o0, o1;
        o0.x = acc[i][0] + bias[0]; o0.y = acc[i][1] + bias[1];
        o0.z = acc[i][2] + bias[2]; o0.w = acc[i][3] + bias[3];
        o1.x = acc[i][4] + bias[4]; o1.y = acc[i][5] + bias[5];
        o1.z = acc[i][6] + bias[6]; o1.w = acc[i][7] + bias[7];
        *(float4*)(HTC + (size_t)mm * N3 + n0 + tx * 8)     = o0;
        *(float4*)(HTC + (size_t)mm * N3 + n0 + tx * 8 + 4) = o1;
    }
}

__device__ __forceinline__ float fast_sig(float x) {
    return __builtin_amdgcn_rcpf(1.f + __expf(-x));
}
__device__ __forceinline__ float fast_tanh(float x) {
    return 2.f * fast_sig(2.f * x) - 1.f;
}

// =====================================================================
// Recurrence: 256 blocks x 512 threads. Compute body is byte-identical
// to the round-1 PASSING kernel. Only the transport changed:
//
// DUAL-RING tagged exchange (3-bit round tag in fp32 mantissa LSBs,
// poll load IS the data load, producers fire-and-forget):
//   - owners publish each dword to exch_l (sc0: serviced by the local
//     XCD L2 when producer+consumer share an XCD) AND exch_g (sc1:
//     device scope, the round-1-proven path).
//   - consumers poll the LOCAL ring up to 48 iters (s_sleep backoff).
//     Hit -> exchange stayed on-XCD (fast). Miss -> per-thread sticky
//     flag, poll the GLOBAL ring (round-1 semantics, deadman-bounded).
// Correctness never depends on block->XCD placement; only speed does.
// =====================================================================
__global__ __launch_bounds__(512, 2) void rhn_scan(
    const float* __restrict__ hidden,
    const float* __restrict__ s_h_mask,
    const float* __restrict__ Wh, const float* __restrict__ bh,
    const float* __restrict__ Wt, const float* __restrict__ bt,
    const float* __restrict__ HTC,
    float* __restrict__ exch_g,      // [2][64][512] tagged ring, device scope
    float* __restrict__ exch_l,      // [2][64][512] tagged ring, XCD-local
    float* __restrict__ out)         // outs [512][64][512] then last [64][512]
{
    __shared__ float sm_s[8][HID];   // masked state, [b-local][k]
    __shared__ float linT[16][8];    // lin_t exchange g1 -> g0

    const int tid  = threadIdx.x;
    const int lane = tid & 63;
    const int w    = tid >> 6;          // wave 0..7
    const int c    = lane & 3;
    const int kq   = (lane >> 2) & 15;  // k-chunk, in lane bits [5:2] for shfl
    const int gh   = w * 4 + c;         // 0..31
    const int g    = gh >> 4;           // 0: Wh side, 1: Wt side
    const int hl   = gh & 15;           // h-row within tile

    const int hi = blockIdx.x >> 3;     // 0..31 h-split
    const int bi = blockIdx.x & 7;      // 0..7  b-group (round-robin => XCD)
    const int h0 = hi * 16, b0 = bi * 8;

    // b owned after kq-reduction (dup at kq and kq+8)
    const int myb = ((kq & 1) << 2) | (kq & 2) | ((kq >> 2) & 1);
    const bool own = (g == 0) && (kq < 8);
    const bool lw  = (g == 1) && (kq < 8);

    // ---- one-time: W slice into registers (5 layers x 8 float4) ----
    const float* Wsrc = g ? Wt : Wh;
    float4 Wreg[DEPTH * 8];
#pragma unroll
    for (int l = 0; l < DEPTH; ++l)
#pragma unroll
        for (int j = 0; j < 8; ++j)
            Wreg[l * 8 + j] = *(const float4*)(Wsrc
                + ((size_t)l * HID + (h0 + hl)) * HID + (size_t)(j * 16 + kq) * 4);

    float biasr[DEPTH];
    const float* bsrc = g ? bt : bh;
#pragma unroll
    for (int l = 0; l < DEPTH; ++l) biasr[l] = bsrc[l * HID + h0 + hl];

    // ---- staging slots: each thread owns 2 float4 of the [8][512] state ----
    const int bA = tid >> 7,  kA = tid & 127;   // b 0..3
    const int bB = bA + 4,    kB = kA;          // b 4..7
    const size_t offA = ((size_t)(b0 + bA) * HID + (size_t)kA * 4) * sizeof(float);
    const size_t offB = ((size_t)(b0 + bB) * HID + (size_t)kB * 4) * sizeof(float);
    const size_t SLOT = (size_t)BATCH * HID * sizeof(float);

    // ---- owner-held state (128 owners/block: g==0 && kq<8) ----
    float s = 0.f, mymask = 0.f, Hp = 0.f, Tp = 0.f, Cp = 0.f;
    size_t ownoff = 0;
    if (own) {
        const int gb = b0 + myb, hh = h0 + hl;
        s      = hidden[(size_t)gb * HID + hh];
        mymask = s_h_mask[(size_t)gb * HID + hh];
        const float* hp = HTC + (size_t)gb * N3 + hh;   // step 0
        Hp = hp[0]; Tp = hp[512]; Cp = hp[1024];
        ownoff = ((size_t)gb * HID + hh) * sizeof(float);
        // publish exchange #0 (slot 0, tag 0) on BOTH rings
        unsigned uu = (__float_as_uint(s * mymask) & ~7u);
        char* pl = (char*)exch_l + ownoff;
        char* pg = (char*)exch_g + ownoff;
        asm volatile("global_store_dword %0, %1, off sc0" :: "v"(pl), "v"(uu) : "memory");
        asm volatile("global_store_dword %0, %1, off sc1" :: "v"(pg), "v"(uu) : "memory");
    }

    const float4* smq = (const float4*)&sm_s[0][0] + kq;

    bool st1 = false;        // sticky: this thread's producer is off-XCD
    int budget = 1 << 23;    // deadman for the global-ring poll (never trips
                             // if sc1 transport behaves as in round 1)
    int seq = 0;
    for (int step = 0; step < S_LEN; ++step) {
#define ROUND(L)                                                                  \
        {                                                                         \
            const unsigned tg = (unsigned)(seq & 7);                              \
            const size_t sbo = (size_t)(seq & 1) * SLOT;                          \
            uintx4 ua, ub;                                                        \
            bool got = false;                                                     \
            if (!st1) {   /* local ring first: XCD-L2 latency if co-located */    \
                const char* pal = (const char*)exch_l + sbo + offA;               \
                const char* pbl = (const char*)exch_l + sbo + offB;               \
                _Pragma("unroll 1")                                               \
                for (int it = 0; it < 48; ++it) {                                 \
                    asm volatile("global_load_dwordx4 %0, %2, off sc0\n\t"        \
                                 "global_load_dwordx4 %1, %3, off sc0\n\t"        \
                                 "s_waitcnt vmcnt(0)"                             \
                                 : "=&v"(ua), "=&v"(ub)                           \
                                 : "v"(pal), "v"(pbl) : "memory");                \
                    unsigned m = ((ua.x ^ tg) | (ua.y ^ tg) | (ua.z ^ tg)         \
                                | (ua.w ^ tg) | (ub.x ^ tg) | (ub.y ^ tg)         \
                                | (ub.z ^ tg) | (ub.w ^ tg)) & 7u;                \
                    if (m == 0u) { got = true; break; }                           \
                    __builtin_amdgcn_s_sleep(1);                                  \
                }                                                                 \
                if (!got) st1 = true;                                             \
            }                                                                     \
            if (!got) {   /* global ring: round-1-proven device-scope path */     \
                const char* pag = (const char*)exch_g + sbo + offA;               \
                const char* pbg = (const char*)exch_g + sbo + offB;               \
                _Pragma("unroll 1")                                               \
                do {                                                              \
                    asm volatile("global_load_dwordx4 %0, %2, off sc1\n\t"        \
                                 "global_load_dwordx4 %1, %3, off sc1\n\t"        \
                                 "s_waitcnt vmcnt(0)"                             \
                                 : "=&v"(ua), "=&v"(ub)                           \
                                 : "v"(pag), "v"(pbg) : "memory");                \
                    unsigned m = ((ua.x ^ tg) | (ua.y ^ tg) | (ua.z ^ tg)         \
                                | (ua.w ^ tg) | (ub.x ^ tg) | (ub.y ^ tg)         \
                                | (ub.z ^ tg) | (ub.w ^ tg)) & 7u;                \
                    if (m == 0u) break;                                           \
                    __builtin_amdgcn_s_sleep(1);                                  \
                } while (--budget > 0);                                           \
            }                                                                     \
            *(uintx4*)&sm_s[bA][kA * 4] = ua;                                     \
            *(uintx4*)&sm_s[bB][kB * 4] = ub;                                     \
            __syncthreads();  /* sync1: staging complete */                       \
            float acc[8] = {0.f, 0.f, 0.f, 0.f, 0.f, 0.f, 0.f, 0.f};              \
            _Pragma("unroll")                                                     \
            for (int j = 0; j < 8; ++j) {                                         \
                const float4 wv = Wreg[(L) * 8 + j];                              \
                _Pragma("unroll")                                                 \
                for (int b = 0; b < 8; ++b) {                                     \
                    const float4 sv = smq[b * 128 + j * 16];                      \
                    acc[b] = fmaf(wv.x, sv.x, acc[b]);                            \
                    acc[b] = fmaf(wv.y, sv.y, acc[b]);                            \
                    acc[b] = fmaf(wv.z, sv.z, acc[b]);                            \
                    acc[b] = fmaf(wv.w, sv.w, acc[b]);                            \
                }                                                                 \
            }                                                                     \
            {   /* reduce over kq (lane bits 2..5), pair-combining tree */        \
                const bool u0 = (lane & 4) != 0;                                  \
                const bool u1 = (lane & 8) != 0;                                  \
                const bool u2 = (lane & 16) != 0;                                 \
                _Pragma("unroll")                                                 \
                for (int i = 0; i < 4; ++i) {                                     \
                    float snd = u0 ? acc[i] : acc[i + 4];                         \
                    float kp  = u0 ? acc[i + 4] : acc[i];                         \
                    acc[i] = kp + __shfl_xor(snd, 4);                             \
                }                                                                 \
                _Pragma("unroll")                                                 \
                for (int i = 0; i < 2; ++i) {                                     \
                    float snd = u1 ? acc[i] : acc[i + 2];                         \
                    float kp  = u1 ? acc[i + 2] : acc[i];                         \
                    acc[i] = kp + __shfl_xor(snd, 8);                             \
                }                                                                 \
                {                                                                 \
                    float snd = u2 ? acc[0] : acc[1];                             \
                    float kp  = u2 ? acc[1] : acc[0];                             \
                    acc[0] = kp + __shfl_xor(snd, 16);                            \
                }                                                                 \
                acc[0] += __shfl_xor(acc[0], 32);                                 \
            }                                                                     \
            const float lin = acc[0] + biasr[L];                                  \
            if (lw) linT[hl][myb] = lin;                                          \
            __syncthreads();  /* sync2: linT ready; all sm reads done */          \
            if (own) {                                                            \
                const float lt = linT[hl][myb];                                   \
                float hv, tv, cv;                                                 \
                if ((L) == 0) {                                                   \
                    hv = fast_tanh(Hp + lin);                                     \
                    tv = fast_sig(Tp + lt);                                       \
                    cv = fast_sig(Cp + lt);                                       \
                } else {                                                          \
                    hv = fast_tanh(lin);                                          \
                    tv = fast_sig(lt);                                            \
                    cv = tv;                                                      \
                }                                                                 \
                s = hv * tv + s * cv;                                             \
                unsigned uu = (__float_as_uint(s * mymask) & ~7u)                 \
                            | (unsigned)((seq + 1) & 7);                          \
                const size_t po = (size_t)((seq + 1) & 1) * SLOT + ownoff;        \
                char* pl = (char*)exch_l + po;                                    \
                char* pg = (char*)exch_g + po;                                    \
                asm volatile("global_store_dword %0, %1, off sc0"                 \
                             :: "v"(pl), "v"(uu) : "memory");                     \
                asm volatile("global_store_dword %0, %1, off sc1"                 \
                             :: "v"(pg), "v"(uu) : "memory");                     \
                if ((L) == DEPTH - 1)                                             \
                    out[((size_t)step * BATCH + (b0 + myb)) * HID + (h0 + hl)] = s; \
                if ((L) == 0 && step + 1 < S_LEN) {                               \
                    const float* hp = HTC + ((size_t)((step + 1) * BATCH          \
                                      + (b0 + myb))) * N3 + (h0 + hl);            \
                    Hp = hp[0]; Tp = hp[512]; Cp = hp[1024];                      \
                }                                                                 \
            }                                                                     \
            ++seq;                                                                \
        }
        ROUND(0) ROUND(1) ROUND(2) ROUND(3) ROUND(4)
#undef ROUND
    }

    // last = outs[S_LEN-1]
    if (own)
        out[(size_t)S_LEN * BATCH * HID + (size_t)(b0 + myb) * HID + (h0 + hl)] = s;
}

extern "C" void kernel_launch(void* const* d_in, const int* in_sizes, int n_in,
                              void* d_out, int out_size, void* d_ws, size_t ws_size,
                              hipStream_t stream) {
    const float* inp      = (const float*)d_in[0];
    const float* hidden   = (const float*)d_in[1];
    const float* h_mask   = (const float*)d_in[2];
    const float* s_h_mask = (const float*)d_in[3];
    const float* Wih = (const float*)d_in[4];
    const float* bih = (const float*)d_in[5];
    const float* Wit = (const float*)d_in[6];
    const float* bit_ = (const float*)d_in[7];
    const float* Wic = (const float*)d_in[8];
    const float* bic = (const float*)d_in[9];
    const float* Wh = (const float*)d_in[10];
    const float* bh = (const float*)d_in[11];
    const float* Wt = (const float*)d_in[12];
    const float* bt = (const float*)d_in[13];
    float* out = (float*)d_out;

    float* HTC    = (float*)d_ws;                      // 32768*1536 f32 = 201.3 MB
    float* exch_g = HTC + (size_t)32768 * N3;          // [2][64][512] f32
    float* exch_l = exch_g + 2 * (size_t)BATCH * HID;  // [2][64][512] f32

    // poison both rings: 0xFFFFFFFF carries tag 7, never a live tag at a
    // slot's first use (slot0 first tag 0, slot1 first tag 1)
    (void)hipMemsetAsync(exch_g, 0xFF, 4 * (size_t)BATCH * HID * sizeof(float), stream);

    // 1) input projections
    dim3 g1(256, 12);
    rhn_inproj<<<g1, 256, 0, stream>>>(inp, h_mask, Wih, Wit, Wic, bih, bit_, bic, HTC);

    // 2) recurrence (cooperative: co-residency for the spin protocol)
    void* args[] = {(void*)&hidden, (void*)&s_h_mask, (void*)&Wh, (void*)&bh,
                    (void*)&Wt, (void*)&bt, (void*)&HTC, (void*)&exch_g,
                    (void*)&exch_l, (void*)&out};
    (void)hipLaunchCooperativeKernel((void*)rhn_scan, dim3(NBLK), dim3(512), args, 0, stream);
}

// Round 8
// 17336.800 us; speedup vs baseline: 1.4924x; 1.0959x over previous
//
#include <hip/hip_runtime.h>
#include <math.h>

#define S_LEN 512
#define BATCH 64
#define IN_DIM 512
#define HID 512
#define DEPTH 5
#define N3 1536  // 3*HID
#define NBLK 256

typedef float floatx4 __attribute__((ext_vector_type(4)));
typedef unsigned int uintx4 __attribute__((ext_vector_type(4)));

// =====================================================================
// Input projection GEMM (unchanged, proven):
//   HTC[m, n] = sum_k (h_mask[m&63, k] * inp[m, k]) * W3[n, k] + b3[n]
// =====================================================================
__global__ __launch_bounds__(256) void rhn_inproj(
    const float* __restrict__ inp, const float* __restrict__ h_mask,
    const float* __restrict__ Wih, const float* __restrict__ Wit,
    const float* __restrict__ Wic, const float* __restrict__ bih,
    const float* __restrict__ bit_, const float* __restrict__ bic,
    float* __restrict__ HTC)
{
    constexpr int BM = 128, BN = 128, BK = 16, LW = BM + 4;
    __shared__ float As[BK][LW];
    __shared__ float Bs[BK][LW];
    const int m0 = blockIdx.x * BM;
    const int n0 = blockIdx.y * BN;
    const int tid = threadIdx.x;
    const int lrow = tid & 127;
    const int lkq  = tid >> 7;
    const int tx = tid & 15, ty = tid >> 4;

    const float* Arow = inp + (size_t)(m0 + lrow) * 512;
    const float* Mrow = h_mask + (size_t)((m0 + lrow) & 63) * 512;
    const int n = n0 + lrow;
    const float* Wrow = (n < 512) ? (Wih + (size_t)n * 512)
                       : (n < 1024) ? (Wit + (size_t)(n - 512) * 512)
                                    : (Wic + (size_t)(n - 1024) * 512);

    float acc[8][8] = {};

    for (int k0 = 0; k0 < 512; k0 += BK) {
#pragma unroll
        for (int it = 0; it < 2; ++it) {
            int kq = lkq * 2 + it;
            float4 av = *(const float4*)(Arow + k0 + kq * 4);
            float4 mv = *(const float4*)(Mrow + k0 + kq * 4);
            float4 bv = *(const float4*)(Wrow + k0 + kq * 4);
            As[kq * 4 + 0][lrow] = av.x * mv.x;
            As[kq * 4 + 1][lrow] = av.y * mv.y;
            As[kq * 4 + 2][lrow] = av.z * mv.z;
            As[kq * 4 + 3][lrow] = av.w * mv.w;
            Bs[kq * 4 + 0][lrow] = bv.x;
            Bs[kq * 4 + 1][lrow] = bv.y;
            Bs[kq * 4 + 2][lrow] = bv.z;
            Bs[kq * 4 + 3][lrow] = bv.w;
        }
        __syncthreads();
#pragma unroll
        for (int kk = 0; kk < BK; ++kk) {
            float4 a0 = *(const float4*)&As[kk][ty * 8];
            float4 a1 = *(const float4*)&As[kk][ty * 8 + 4];
            float4 bv0 = *(const float4*)&Bs[kk][tx * 8];
            float4 bv1 = *(const float4*)&Bs[kk][tx * 8 + 4];
            float am[8] = {a0.x, a0.y, a0.z, a0.w, a1.x, a1.y, a1.z, a1.w};
            float bn[8] = {bv0.x, bv0.y, bv0.z, bv0.w, bv1.x, bv1.y, bv1.z, bv1.w};
#pragma unroll
            for (int i = 0; i < 8; ++i)
#pragma unroll
                for (int j = 0; j < 8; ++j)
                    acc[i][j] += am[i] * bn[j];
        }
        __syncthreads();
    }

    float bias[8];
#pragma unroll
    for (int j = 0; j < 8; ++j) {
        int nn = n0 + tx * 8 + j;
        bias[j] = (nn < 512) ? bih[nn] : (nn < 1024) ? bit_[nn - 512] : bic[nn - 1024];
    }
#pragma unroll
    for (int i = 0; i < 8; ++i) {
        int mm = m0 + ty * 8 + i;
        float4 o0, o1;
        o0.x = acc[i][0] + bias[0]; o0.y = acc[i][1] + bias[1];
        o0.z = acc[i][2] + bias[2]; o0.w = acc[i][3] + bias[3];
        o1.x = acc[i][4] + bias[4]; o1.y = acc[i][5] + bias[5];
        o1.z = acc[i][6] + bias[6]; o1.w = acc[i][7] + bias[7];
        *(float4*)(HTC + (size_t)mm * N3 + n0 + tx * 8)     = o0;
        *(float4*)(HTC + (size_t)mm * N3 + n0 + tx * 8 + 4) = o1;
    }
}

__device__ __forceinline__ float fast_sig(float x) {
    return __builtin_amdgcn_rcpf(1.f + __expf(-x));
}
__device__ __forceinline__ float fast_tanh(float x) {
    return 2.f * fast_sig(2.f * x) - 1.f;
}

// =====================================================================
// Recurrence: byte-identical to the round-1 PASSING kernel except the
// occupancy directive: amdgpu_waves_per_eu(2,2) pins the target at
// exactly 2 waves/SIMD (the 8-wave block alone on its CU), giving the
// register allocator the full 256-VGPR budget so the 40xfloat4 W slice
// (160 VGPRs) truly stays register-resident. Prior builds capped at 128
// VGPRs and re-loaded W from L2/MALL every round (the 17% VALUBusy).
// Transport: round-1-proven tagged sc1 ring (3-bit round tag in fp32
// mantissa LSBs; poll load IS the data load; fire-and-forget stores).
// =====================================================================
__global__ __attribute__((amdgpu_waves_per_eu(2, 2))) __launch_bounds__(512)
void rhn_scan(
    const float* __restrict__ hidden,
    const float* __restrict__ s_h_mask,
    const float* __restrict__ Wh, const float* __restrict__ bh,
    const float* __restrict__ Wt, const float* __restrict__ bt,
    const float* __restrict__ HTC,
    float* __restrict__ exch,    // [2][64][512] tagged masked-state ring
    float* __restrict__ out)     // outs [512][64][512] then last [64][512]
{
    __shared__ float sm_s[8][HID];   // masked state, [b-local][k]
    __shared__ float linT[16][8];    // lin_t exchange g1 -> g0

    const int tid  = threadIdx.x;
    const int lane = tid & 63;
    const int w    = tid >> 6;          // wave 0..7
    const int c    = lane & 3;
    const int kq   = (lane >> 2) & 15;  // k-chunk, in lane bits [5:2] for shfl
    const int gh   = w * 4 + c;         // 0..31
    const int g    = gh >> 4;           // 0: Wh side, 1: Wt side
    const int hl   = gh & 15;           // h-row within tile

    const int hi = blockIdx.x >> 3;     // 0..31 h-split
    const int bi = blockIdx.x & 7;      // 0..7  b-group
    const int h0 = hi * 16, b0 = bi * 8;

    // b owned after kq-reduction (dup at kq and kq+8)
    const int myb = ((kq & 1) << 2) | (kq & 2) | ((kq >> 2) & 1);
    const bool own = (g == 0) && (kq < 8);
    const bool lw  = (g == 1) && (kq < 8);

    // ---- one-time: W slice into registers (5 layers x 8 float4) ----
    // thread's k-set: float4 indices { j*16+kq : j=0..7 } of row h0+hl
    const float* Wsrc = g ? Wt : Wh;
    float4 Wreg[DEPTH * 8];
#pragma unroll
    for (int l = 0; l < DEPTH; ++l)
#pragma unroll
        for (int j = 0; j < 8; ++j)
            Wreg[l * 8 + j] = *(const float4*)(Wsrc
                + ((size_t)l * HID + (h0 + hl)) * HID + (size_t)(j * 16 + kq) * 4);

    float biasr[DEPTH];
    const float* bsrc = g ? bt : bh;
#pragma unroll
    for (int l = 0; l < DEPTH; ++l) biasr[l] = bsrc[l * HID + h0 + hl];

    // ---- staging slots: each thread owns 2 float4 of the [8][512] state ----
    const int pA = tid,       b_0 = pA >> 7, i40 = pA & 127;
    const int pB = tid + 512, b_1 = pB >> 7, i41 = pB & 127;
    const size_t offA = ((size_t)(b0 + b_0) * HID + (size_t)i40 * 4) * sizeof(float);
    const size_t offB = ((size_t)(b0 + b_1) * HID + (size_t)i41 * 4) * sizeof(float);
    const size_t SLOT = (size_t)BATCH * HID * sizeof(float);

    // ---- owner-held state (128 owners/block: g==0 && kq<8) ----
    float s = 0.f, mymask = 0.f, Hp = 0.f, Tp = 0.f, Cp = 0.f;
    size_t ownoff = 0;
    if (own) {
        const int gb = b0 + myb, hh = h0 + hl;
        s      = hidden[(size_t)gb * HID + hh];
        mymask = s_h_mask[(size_t)gb * HID + hh];
        const float* hp = HTC + (size_t)gb * N3 + hh;   // step 0
        Hp = hp[0]; Tp = hp[512]; Cp = hp[1024];
        ownoff = ((size_t)gb * HID + hh) * sizeof(float);
        // publish exchange #0 (slot 0, tag 0): masked initial state
        unsigned uu = (__float_as_uint(s * mymask) & ~7u);
        char* p = (char*)exch + ownoff;
        asm volatile("global_store_dword %0, %1, off sc1" :: "v"(p), "v"(uu) : "memory");
    }

    const float4* smq = (const float4*)&sm_s[0][0] + kq;

    int seq = 0;
    for (int step = 0; step < S_LEN; ++step) {
#define ROUND(L)                                                                  \
        {                                                                         \
            const unsigned tg = (unsigned)(seq & 7);                              \
            const char* sb = (const char*)exch + (size_t)(seq & 1) * SLOT;        \
            const char* pa = sb + offA;                                           \
            const char* pb = sb + offB;                                           \
            uintx4 ua, ub;                                                        \
            for (;;) {                                                            \
                asm volatile("global_load_dwordx4 %0, %2, off sc1\n\t"            \
                             "global_load_dwordx4 %1, %3, off sc1\n\t"            \
                             "s_waitcnt vmcnt(0)"                                 \
                             : "=&v"(ua), "=&v"(ub)                               \
                             : "v"(pa), "v"(pb) : "memory");                      \
                unsigned mm = (ua.x ^ tg) | (ua.y ^ tg) | (ua.z ^ tg) | (ua.w ^ tg) \
                            | (ub.x ^ tg) | (ub.y ^ tg) | (ub.z ^ tg) | (ub.w ^ tg); \
                if ((mm & 7u) == 0u) break;                                       \
            }                                                                     \
            *(uintx4*)&sm_s[b_0][i40 * 4] = ua;                                   \
            *(uintx4*)&sm_s[b_1][i41 * 4] = ub;                                   \
            __syncthreads();  /* sync1: staging complete */                       \
            float acc[8] = {0.f, 0.f, 0.f, 0.f, 0.f, 0.f, 0.f, 0.f};              \
            _Pragma("unroll")                                                     \
            for (int j = 0; j < 8; ++j) {                                         \
                const float4 wv = Wreg[(L) * 8 + j];                              \
                _Pragma("unroll")                                                 \
                for (int b = 0; b < 8; ++b) {                                     \
                    const float4 sv = smq[b * 128 + j * 16];                      \
                    acc[b] = fmaf(wv.x, sv.x, acc[b]);                            \
                    acc[b] = fmaf(wv.y, sv.y, acc[b]);                            \
                    acc[b] = fmaf(wv.z, sv.z, acc[b]);                            \
                    acc[b] = fmaf(wv.w, sv.w, acc[b]);                            \
                }                                                                 \
            }                                                                     \
            {   /* reduce over kq (lane bits 2..5), pair-combining tree */        \
                const bool u0 = (lane & 4) != 0;                                  \
                const bool u1 = (lane & 8) != 0;                                  \
                const bool u2 = (lane & 16) != 0;                                 \
                _Pragma("unroll")                                                 \
                for (int i = 0; i < 4; ++i) {                                     \
                    float snd = u0 ? acc[i] : acc[i + 4];                         \
                    float kp  = u0 ? acc[i + 4] : acc[i];                         \
                    acc[i] = kp + __shfl_xor(snd, 4);                             \
                }                                                                 \
                _Pragma("unroll")                                                 \
                for (int i = 0; i < 2; ++i) {                                     \
                    float snd = u1 ? acc[i] : acc[i + 2];                         \
                    float kp  = u1 ? acc[i + 2] : acc[i];                         \
                    acc[i] = kp + __shfl_xor(snd, 8);                             \
                }                                                                 \
                {                                                                 \
                    float snd = u2 ? acc[0] : acc[1];                             \
                    float kp  = u2 ? acc[1] : acc[0];                             \
                    acc[0] = kp + __shfl_xor(snd, 16);                            \
                }                                                                 \
                acc[0] += __shfl_xor(acc[0], 32);                                 \
            }                                                                     \
            const float lin = acc[0] + biasr[L];                                  \
            if (lw) linT[hl][myb] = lin;                                          \
            __syncthreads();  /* sync2: linT ready; all sm reads done */          \
            if (own) {                                                            \
                const float lt = linT[hl][myb];                                   \
                float hv, tv, cv;                                                 \
                if ((L) == 0) {                                                   \
                    hv = fast_tanh(Hp + lin);                                     \
                    tv = fast_sig(Tp + lt);                                       \
                    cv = fast_sig(Cp + lt);                                       \
                } else {                                                          \
                    hv = fast_tanh(lin);                                          \
                    tv = fast_sig(lt);                                            \
                    cv = tv;                                                      \
                }                                                                 \
                s = hv * tv + s * cv;                                             \
                unsigned uu = (__float_as_uint(s * mymask) & ~7u)                 \
                            | (unsigned)((seq + 1) & 7);                          \
                char* p = (char*)exch + (size_t)((seq + 1) & 1) * SLOT + ownoff;  \
                asm volatile("global_store_dword %0, %1, off sc1"                 \
                             :: "v"(p), "v"(uu) : "memory");                      \
                if ((L) == DEPTH - 1)                                             \
                    out[((size_t)step * BATCH + (b0 + myb)) * HID + (h0 + hl)] = s; \
                if ((L) == 0 && step + 1 < S_LEN) {                               \
                    const float* hp = HTC + ((size_t)((step + 1) * BATCH         \
                                      + (b0 + myb))) * N3 + (h0 + hl);            \
                    Hp = hp[0]; Tp = hp[512]; Cp = hp[1024];                      \
                }                                                                 \
            }                                                                     \
            ++seq;                                                                \
        }
        ROUND(0) ROUND(1) ROUND(2) ROUND(3) ROUND(4)
#undef ROUND
    }

    // last = outs[S_LEN-1]
    if (own)
        out[(size_t)S_LEN * BATCH * HID + (size_t)(b0 + myb) * HID + (h0 + hl)] = s;
}

extern "C" void kernel_launch(void* const* d_in, const int* in_sizes, int n_in,
                              void* d_out, int out_size, void* d_ws, size_t ws_size,
                              hipStream_t stream) {
    const float* inp      = (const float*)d_in[0];
    const float* hidden   = (const float*)d_in[1];
    const float* h_mask   = (const float*)d_in[2];
    const float* s_h_mask = (const float*)d_in[3];
    const float* Wih = (const float*)d_in[4];
    const float* bih = (const float*)d_in[5];
    const float* Wit = (const float*)d_in[6];
    const float* bit_ = (const float*)d_in[7];
    const float* Wic = (const float*)d_in[8];
    const float* bic = (const float*)d_in[9];
    const float* Wh = (const float*)d_in[10];
    const float* bh = (const float*)d_in[11];
    const float* Wt = (const float*)d_in[12];
    const float* bt = (const float*)d_in[13];
    float* out = (float*)d_out;

    float* HTC  = (float*)d_ws;                    // 32768*1536 f32 = 201.3 MB
    float* exch = HTC + (size_t)32768 * N3;        // 2*64*512 f32 ring

    // poison ring slots: 0xFFFFFFFF has mantissa-LSB tag 7, never a live tag
    // at a slot's first use (slot0 first tag 0, slot1 first tag 1)
    (void)hipMemsetAsync(exch, 0xFF, 2 * (size_t)BATCH * HID * sizeof(float), stream);

    // 1) input projections
    dim3 g1(256, 12);
    rhn_inproj<<<g1, 256, 0, stream>>>(inp, h_mask, Wih, Wit, Wic, bih, bit_, bic, HTC);

    // 2) recurrence (cooperative: guarantees co-residency for the spin protocol)
    void* args[] = {(void*)&hidden, (void*)&s_h_mask, (void*)&Wh, (void*)&bh,
                    (void*)&Wt, (void*)&bt, (void*)&HTC, (void*)&exch, (void*)&out};
    (void)hipLaunchCooperativeKernel((void*)rhn_scan, dim3(NBLK), dim3(512), args, 0, stream);
}